// Round 1
// baseline (6016.298 us; speedup 1.0000x reference)
//
#include <hip/hip_runtime.h>

#define NN 100000
#define D 64

// ---- degree via float atomics (counts are small integers, exact in fp32) ----
__global__ void k_degree(const int* __restrict__ src, const int* __restrict__ dst,
                         float* __restrict__ deg_out, float* __restrict__ deg_in, int E) {
    int e = blockIdx.x * blockDim.x + threadIdx.x;
    if (e < E) {
        atomicAdd(&deg_out[src[e]], 1.0f);
        atomicAdd(&deg_in[dst[e]], 1.0f);
    }
}

// ---- in-place deg -> deg^-1/2 with clip(deg,1) ----
__global__ void k_norm(float* __restrict__ ns, float* __restrict__ nd, int n) {
    int i = blockIdx.x * blockDim.x + threadIdx.x;
    if (i < n) {
        ns[i] = rsqrtf(fmaxf(ns[i], 1.0f));
        nd[i] = rsqrtf(fmaxf(nd[i], 1.0f));
    }
}

// ---- xs = x * norm_s (row-wise), float4 ----
__global__ void k_scale(const float* __restrict__ x, const float* __restrict__ ns,
                        float* __restrict__ xs, int n16) {
    int i = blockIdx.x * blockDim.x + threadIdx.x;
    if (i < n16) {
        float s = ns[i >> 4];
        float4 v = ((const float4*)x)[i];
        v.x *= s; v.y *= s; v.z *= s; v.w *= s;
        ((float4*)xs)[i] = v;
    }
}

// ---- per-edge scatter-add: agg[dst] += ew * xs[src], 16 threads/edge ----
__global__ void k_scatter(const int* __restrict__ src, const int* __restrict__ dst,
                          const float* __restrict__ ew, const float* __restrict__ xs,
                          float* __restrict__ agg, int E) {
    int idx = blockIdx.x * blockDim.x + threadIdx.x;
    int e = idx >> 4;
    if (e >= E) return;
    int c = (idx & 15) << 2;
    int s = src[e];
    int d = dst[e];
    float w = ew[e];
    float4 v = *(const float4*)(xs + (size_t)s * D + c);
    float* a = agg + (size_t)d * D + c;
    atomicAdd(a + 0, w * v.x);
    atomicAdd(a + 1, w * v.y);
    atomicAdd(a + 2, w * v.z);
    atomicAdd(a + 3, w * v.w);
}

// ---- node-wise GEMM: out[v] = epilogue( (in[v] * (SCALE_IN?nd[v]:1)) @ W + b ) ----
// epilogue: +res (before relu), relu, *ns
template<int OUTD, bool RELU, bool SCALE_IN, bool SCALE_OUT, bool ADD_RES>
__global__ void k_gemm(const float* __restrict__ in, const float* __restrict__ W,
                       const float* __restrict__ bias, const float* __restrict__ nd,
                       const float* __restrict__ ns, const float* __restrict__ res,
                       float* __restrict__ out, int n) {
    constexpr int NPB = 256 / OUTD;   // nodes per block
    __shared__ float sW[D * OUTD];
    __shared__ float sIn[NPB][D];
    int tid = threadIdx.x;
    for (int i = tid; i < D * OUTD; i += 256) sW[i] = W[i];
    int node0 = blockIdx.x * NPB;
    for (int i = tid; i < NPB * D; i += 256) {
        int ln = i / D, d = i % D;
        int node = node0 + ln;
        float v = 0.f;
        if (node < n) {
            v = in[(size_t)node * D + d];
            if (SCALE_IN) v *= nd[node];
        }
        sIn[ln][d] = v;
    }
    __syncthreads();
    int ln = tid / OUTD;
    int f = tid % OUTD;
    int node = node0 + ln;
    if (node >= n) return;
    float acc = bias[f];
    #pragma unroll
    for (int d = 0; d < D; ++d)
        acc += sIn[ln][d] * sW[d * OUTD + f];
    if (ADD_RES) acc += res[(size_t)node * OUTD + f];
    if (RELU) acc = fmaxf(acc, 0.f);
    if (SCALE_OUT) acc *= ns[node];
    out[(size_t)node * OUTD + f] = acc;
}

extern "C" void kernel_launch(void* const* d_in, const int* in_sizes, int n_in,
                              void* d_out, int out_size, void* d_ws, size_t ws_size,
                              hipStream_t stream) {
    const float* x   = (const float*)d_in[0];
    const int*   src = (const int*)d_in[1];
    const int*   dst = (const int*)d_in[2];
    const float* ew  = (const float*)d_in[3];
    const float* Wl[4] = {(const float*)d_in[4], (const float*)d_in[6],
                          (const float*)d_in[8], (const float*)d_in[10]};
    const float* bl[4] = {(const float*)d_in[5], (const float*)d_in[7],
                          (const float*)d_in[9], (const float*)d_in[11]};
    const float* Wr = (const float*)d_in[12];
    const float* br = (const float*)d_in[13];
    const float* Wo = (const float*)d_in[14];
    const float* bo = (const float*)d_in[15];
    float* out = (float*)d_out;

    const int N = NN;
    const int E = in_sizes[1];

    float* ws     = (float*)d_ws;
    float* norm_s = ws;                     // N
    float* norm_d = ws + N;                 // N
    float* xs     = ws + 2 * (size_t)N;     // N*64 (current layer input, pre-scaled by norm_s)
    float* agg    = xs + (size_t)N * D;     // N*64
    float* res    = agg + (size_t)N * D;    // N*64

    hipMemsetAsync(norm_s, 0, 2 * (size_t)N * sizeof(float), stream);
    k_degree<<<(E + 255) / 256, 256, 0, stream>>>(src, dst, norm_s, norm_d, E);
    k_norm<<<(N + 255) / 256, 256, 0, stream>>>(norm_s, norm_d, N);
    k_scale<<<(N * 16 + 255) / 256, 256, 0, stream>>>(x, norm_s, xs, N * 16);
    // res = x @ Wr + br (raw x, no scaling/relu)
    k_gemm<64, false, false, false, false><<<(N + 3) / 4, 256, 0, stream>>>(
        x, Wr, br, nullptr, nullptr, nullptr, res, N);

    for (int l = 0; l < 4; ++l) {
        hipMemsetAsync(agg, 0, (size_t)N * D * sizeof(float), stream);
        k_scatter<<<((size_t)E * 16 + 255) / 256, 256, 0, stream>>>(src, dst, ew, xs, agg, E);
        if (l < 3) {
            // xs = relu((agg*nd)@W + b) * ns   (pre-scaled for next gather)
            k_gemm<64, true, true, true, false><<<(N + 3) / 4, 256, 0, stream>>>(
                agg, Wl[l], bl[l], norm_d, norm_s, nullptr, xs, N);
        } else {
            // xs = relu((agg*nd)@W4 + b4 + res)
            k_gemm<64, true, true, false, true><<<(N + 3) / 4, 256, 0, stream>>>(
                agg, Wl[l], bl[l], norm_d, nullptr, res, xs, N);
        }
    }
    // out = xs @ Wo + bo
    k_gemm<32, false, false, false, false><<<(N + 7) / 8, 256, 0, stream>>>(
        xs, Wo, bo, nullptr, nullptr, nullptr, out, N);
}

// Round 2
// 1051.794 us; speedup vs baseline: 5.7200x; 5.7200x over previous
//
#include <hip/hip_runtime.h>

#define NN 100000
#define D 64

// ---- int degree counts ----
__global__ void k_count(const int* __restrict__ src, const int* __restrict__ dst,
                        int* __restrict__ cnt_out, int* __restrict__ cnt_in, int E) {
    int e = blockIdx.x * blockDim.x + threadIdx.x;
    if (e < E) {
        atomicAdd(&cnt_out[src[e]], 1);
        atomicAdd(&cnt_in[dst[e]], 1);
    }
}

// ---- norms from counts: deg^-1/2 with clip(deg,1) ----
__global__ void k_norm(const int* __restrict__ co, const int* __restrict__ ci,
                       float* __restrict__ ns, float* __restrict__ nd, int n) {
    int i = blockIdx.x * blockDim.x + threadIdx.x;
    if (i < n) {
        ns[i] = rsqrtf(fmaxf((float)co[i], 1.0f));
        nd[i] = rsqrtf(fmaxf((float)ci[i], 1.0f));
    }
}

// ---- xs = x * norm_s (row-wise), float4 ----
__global__ void k_scale(const float* __restrict__ x, const float* __restrict__ ns,
                        float* __restrict__ xs, int n16) {
    int i = blockIdx.x * blockDim.x + threadIdx.x;
    if (i < n16) {
        float s = ns[i >> 4];
        float4 v = ((const float4*)x)[i];
        v.x *= s; v.y *= s; v.z *= s; v.w *= s;
        ((float4*)xs)[i] = v;
    }
}

// ---- exclusive scan, phase 1: each block scans 1024 ints (256 thr x 4) ----
__global__ void k_scan1(const int* __restrict__ in, int* __restrict__ out,
                        int* __restrict__ bsum, int n) {
    __shared__ int lds[256];
    int t = threadIdx.x;
    int base = blockIdx.x * 1024 + t * 4;
    int a0 = 0, a1 = 0, a2 = 0, a3 = 0;
    if (base + 3 < n) {
        int4 v = *(const int4*)(in + base);
        a0 = v.x; a1 = v.y; a2 = v.z; a3 = v.w;
    } else {
        if (base + 0 < n) a0 = in[base + 0];
        if (base + 1 < n) a1 = in[base + 1];
        if (base + 2 < n) a2 = in[base + 2];
        if (base + 3 < n) a3 = in[base + 3];
    }
    lds[t] = a0 + a1 + a2 + a3;
    __syncthreads();
    for (int off = 1; off < 256; off <<= 1) {
        int val = lds[t];
        int add = (t >= off) ? lds[t - off] : 0;
        __syncthreads();
        lds[t] = val + add;
        __syncthreads();
    }
    if (t == 255) bsum[blockIdx.x] = lds[255];
    int o0 = (t > 0) ? lds[t - 1] : 0;
    int o1 = o0 + a0, o2 = o1 + a1, o3 = o2 + a2;
    if (base + 0 < n) out[base + 0] = o0;
    if (base + 1 < n) out[base + 1] = o1;
    if (base + 2 < n) out[base + 2] = o2;
    if (base + 3 < n) out[base + 3] = o3;
}

// ---- phase 2: exclusive scan of block sums (nb <= 128), one block ----
__global__ void k_scan2(int* __restrict__ bsum, int nb) {
    __shared__ int lds[128];
    int t = threadIdx.x;
    lds[t] = (t < nb) ? bsum[t] : 0;
    __syncthreads();
    for (int off = 1; off < 128; off <<= 1) {
        int val = lds[t];
        int add = (t >= off) ? lds[t - off] : 0;
        __syncthreads();
        lds[t] = val + add;
        __syncthreads();
    }
    if (t < nb) bsum[t] = (t > 0) ? lds[t - 1] : 0;
}

// ---- phase 3: add block offsets; copy to cursor; rowptr[n] = E ----
__global__ void k_scan3(int* __restrict__ rowptr, const int* __restrict__ bsum,
                        int* __restrict__ cur, int n, int E) {
    int i = blockIdx.x * blockDim.x + threadIdx.x;
    if (i < n) {
        int v = rowptr[i] + bsum[i >> 10];
        rowptr[i] = v;
        cur[i] = v;
    }
    if (i == 0) rowptr[n] = E;
}

// ---- CSR fill: bucket edges by dst ----
__global__ void k_fill(const int* __restrict__ src, const int* __restrict__ dst,
                       const float* __restrict__ ew, int* __restrict__ cur,
                       int* __restrict__ col, float* __restrict__ wgt, int E) {
    int e = blockIdx.x * blockDim.x + threadIdx.x;
    if (e < E) {
        int d = dst[e];
        int p = atomicAdd(&cur[d], 1);
        col[p] = src[e];
        wgt[p] = ew[e];
    }
}

// ---- gather-reduce: one wave per dst node, lane = feature column ----
__global__ void k_gather(const int* __restrict__ rowptr, const int* __restrict__ col,
                         const float* __restrict__ wgt, const float* __restrict__ xs,
                         float* __restrict__ agg, int n) {
    int node = blockIdx.x * (blockDim.x >> 6) + (threadIdx.x >> 6);
    int lane = threadIdx.x & 63;
    if (node >= n) return;
    int beg = rowptr[node], end = rowptr[node + 1];
    float acc = 0.f;
    for (int base = beg; base < end; base += 64) {
        int e = base + lane;
        int c = 0;
        float w = 0.f;
        if (e < end) { c = col[e]; w = wgt[e]; }
        int cnt = min(end - base, 64);
        for (int j = 0; j < cnt; ++j) {
            int s = __shfl(c, j);
            float w2 = __shfl(w, j);
            acc += w2 * xs[s * D + lane];
        }
    }
    agg[(size_t)node * D + lane] = acc;
}

// ---- node-wise GEMM: out[v] = epilogue( (in[v] * (SCALE_IN?nd[v]:1)) @ W + b ) ----
template<int OUTD, bool RELU, bool SCALE_IN, bool SCALE_OUT, bool ADD_RES>
__global__ void k_gemm(const float* __restrict__ in, const float* __restrict__ W,
                       const float* __restrict__ bias, const float* __restrict__ nd,
                       const float* __restrict__ ns, const float* __restrict__ res,
                       float* __restrict__ out, int n) {
    constexpr int NPB = 256 / OUTD;   // nodes per block
    __shared__ float sW[D * OUTD];
    __shared__ float sIn[NPB][D];
    int tid = threadIdx.x;
    for (int i = tid; i < D * OUTD; i += 256) sW[i] = W[i];
    int node0 = blockIdx.x * NPB;
    for (int i = tid; i < NPB * D; i += 256) {
        int ln = i / D, d = i % D;
        int node = node0 + ln;
        float v = 0.f;
        if (node < n) {
            v = in[(size_t)node * D + d];
            if (SCALE_IN) v *= nd[node];
        }
        sIn[ln][d] = v;
    }
    __syncthreads();
    int ln = tid / OUTD;
    int f = tid % OUTD;
    int node = node0 + ln;
    if (node >= n) return;
    float acc = bias[f];
    #pragma unroll
    for (int d = 0; d < D; ++d)
        acc += sIn[ln][d] * sW[d * OUTD + f];
    if (ADD_RES) acc += res[(size_t)node * OUTD + f];
    if (RELU) acc = fmaxf(acc, 0.f);
    if (SCALE_OUT) acc *= ns[node];
    out[(size_t)node * OUTD + f] = acc;
}

extern "C" void kernel_launch(void* const* d_in, const int* in_sizes, int n_in,
                              void* d_out, int out_size, void* d_ws, size_t ws_size,
                              hipStream_t stream) {
    const float* x   = (const float*)d_in[0];
    const int*   src = (const int*)d_in[1];
    const int*   dst = (const int*)d_in[2];
    const float* ew  = (const float*)d_in[3];
    const float* Wl[4] = {(const float*)d_in[4], (const float*)d_in[6],
                          (const float*)d_in[8], (const float*)d_in[10]};
    const float* bl[4] = {(const float*)d_in[5], (const float*)d_in[7],
                          (const float*)d_in[9], (const float*)d_in[11]};
    const float* Wr = (const float*)d_in[12];
    const float* br = (const float*)d_in[13];
    const float* Wo = (const float*)d_in[14];
    const float* bo = (const float*)d_in[15];
    float* out = (float*)d_out;

    const int N = NN;
    const int E = in_sizes[1];

    // workspace layout (all 4-byte elements); total ~92 MB
    float* ws     = (float*)d_ws;
    float* norm_s = ws;                          // N
    float* norm_d = norm_s + N;                  // N
    float* xs     = norm_d + N;                  // N*D
    float* agg    = xs + (size_t)N * D;          // N*D
    float* res    = agg + (size_t)N * D;         // N*D
    int*   cnt_o  = (int*)(res + (size_t)N * D); // N
    int*   cnt_i  = cnt_o + N;                   // N
    int*   rowptr = cnt_i + N;                   // N+1
    int*   cur    = rowptr + N + 1;              // N
    int*   bsum   = cur + N;                     // 128
    int*   col    = bsum + 128;                  // E
    float* wgt    = (float*)(col + E);           // E

    // ---- degrees + norms ----
    hipMemsetAsync(cnt_o, 0, 2 * (size_t)N * sizeof(int), stream);
    k_count<<<(E + 255) / 256, 256, 0, stream>>>(src, dst, cnt_o, cnt_i, E);
    k_norm<<<(N + 255) / 256, 256, 0, stream>>>(cnt_o, cnt_i, norm_s, norm_d, N);

    // ---- CSR build (by dst) ----
    int nb = (N + 1023) / 1024;  // 98
    k_scan1<<<nb, 256, 0, stream>>>(cnt_i, rowptr, bsum, N);
    k_scan2<<<1, 128, 0, stream>>>(bsum, nb);
    k_scan3<<<(N + 255) / 256, 256, 0, stream>>>(rowptr, bsum, cur, N, E);
    k_fill<<<(E + 255) / 256, 256, 0, stream>>>(src, dst, ew, cur, col, wgt, E);

    // ---- xs = x * norm_s; res = x @ Wr + br ----
    k_scale<<<(N * 16 + 255) / 256, 256, 0, stream>>>(x, norm_s, xs, N * 16);
    k_gemm<64, false, false, false, false><<<(N + 3) / 4, 256, 0, stream>>>(
        x, Wr, br, nullptr, nullptr, nullptr, res, N);

    // ---- 4 GCN layers ----
    for (int l = 0; l < 4; ++l) {
        k_gather<<<(N + 3) / 4, 256, 0, stream>>>(rowptr, col, wgt, xs, agg, N);
        if (l < 3) {
            // xs = relu((agg*nd)@W + b) * ns   (pre-scaled for next gather)
            k_gemm<64, true, true, true, false><<<(N + 3) / 4, 256, 0, stream>>>(
                agg, Wl[l], bl[l], norm_d, norm_s, nullptr, xs, N);
        } else {
            // xs = relu((agg*nd)@W4 + b4 + res)
            k_gemm<64, true, true, false, true><<<(N + 3) / 4, 256, 0, stream>>>(
                agg, Wl[l], bl[l], norm_d, nullptr, res, xs, N);
        }
    }
    // ---- out = xs @ Wo + bo ----
    k_gemm<32, false, false, false, false><<<(N + 7) / 8, 256, 0, stream>>>(
        xs, Wo, bo, nullptr, nullptr, nullptr, out, N);
}

// Round 3
// 894.494 us; speedup vs baseline: 6.7259x; 1.1759x over previous
//
#include <hip/hip_runtime.h>

#define NN 100000
#define D 64
#define R 4   // atomic-spreading replicas

// ---- degree counts into 4 replicas each (contention /4) ----
__global__ void k_count(const int* __restrict__ src, const int* __restrict__ dst,
                        int* __restrict__ cnt_o4, int* __restrict__ cnt_i4, int E) {
    int e = blockIdx.x * blockDim.x + threadIdx.x;
    if (e < E) {
        int r = (threadIdx.x & 3) * NN;
        atomicAdd(&cnt_o4[r + src[e]], 1);
        atomicAdd(&cnt_i4[r + dst[e]], 1);
    }
}

// ---- norms from replica sums; also emit per-node in-degree total ----
__global__ void k_norm(const int* __restrict__ co4, const int* __restrict__ ci4,
                       float* __restrict__ ns, float* __restrict__ nd,
                       int* __restrict__ tot_in, int n) {
    int i = blockIdx.x * blockDim.x + threadIdx.x;
    if (i < n) {
        int o = co4[i] + co4[NN + i] + co4[2 * NN + i] + co4[3 * NN + i];
        int c = ci4[i] + ci4[NN + i] + ci4[2 * NN + i] + ci4[3 * NN + i];
        ns[i] = rsqrtf(fmaxf((float)o, 1.0f));
        nd[i] = rsqrtf(fmaxf((float)c, 1.0f));
        tot_in[i] = c;
    }
}

// ---- xs = x * norm_s (row-wise), float4 ----
__global__ void k_scale(const float* __restrict__ x, const float* __restrict__ ns,
                        float* __restrict__ xs, int n16) {
    int i = blockIdx.x * blockDim.x + threadIdx.x;
    if (i < n16) {
        float s = ns[i >> 4];
        float4 v = ((const float4*)x)[i];
        v.x *= s; v.y *= s; v.z *= s; v.w *= s;
        ((float4*)xs)[i] = v;
    }
}

// ---- exclusive scan, phase 1: each block scans 1024 ints (256 thr x 4) ----
__global__ void k_scan1(const int* __restrict__ in, int* __restrict__ out,
                        int* __restrict__ bsum, int n) {
    __shared__ int lds[256];
    int t = threadIdx.x;
    int base = blockIdx.x * 1024 + t * 4;
    int a0 = 0, a1 = 0, a2 = 0, a3 = 0;
    if (base + 3 < n) {
        int4 v = *(const int4*)(in + base);
        a0 = v.x; a1 = v.y; a2 = v.z; a3 = v.w;
    } else {
        if (base + 0 < n) a0 = in[base + 0];
        if (base + 1 < n) a1 = in[base + 1];
        if (base + 2 < n) a2 = in[base + 2];
        if (base + 3 < n) a3 = in[base + 3];
    }
    lds[t] = a0 + a1 + a2 + a3;
    __syncthreads();
    for (int off = 1; off < 256; off <<= 1) {
        int val = lds[t];
        int add = (t >= off) ? lds[t - off] : 0;
        __syncthreads();
        lds[t] = val + add;
        __syncthreads();
    }
    if (t == 255) bsum[blockIdx.x] = lds[255];
    int o0 = (t > 0) ? lds[t - 1] : 0;
    int o1 = o0 + a0, o2 = o1 + a1, o3 = o2 + a2;
    if (base + 0 < n) out[base + 0] = o0;
    if (base + 1 < n) out[base + 1] = o1;
    if (base + 2 < n) out[base + 2] = o2;
    if (base + 3 < n) out[base + 3] = o3;
}

// ---- phase 2: exclusive scan of block sums (nb <= 128), one block ----
__global__ void k_scan2(int* __restrict__ bsum, int nb) {
    __shared__ int lds[128];
    int t = threadIdx.x;
    lds[t] = (t < nb) ? bsum[t] : 0;
    __syncthreads();
    for (int off = 1; off < 128; off <<= 1) {
        int val = lds[t];
        int add = (t >= off) ? lds[t - off] : 0;
        __syncthreads();
        lds[t] = val + add;
        __syncthreads();
    }
    if (t < nb) bsum[t] = (t > 0) ? lds[t - 1] : 0;
}

// ---- phase 3: add block offsets; rowptr[n] = E ----
__global__ void k_scan3(int* __restrict__ rowptr, const int* __restrict__ bsum,
                        int n, int E) {
    int i = blockIdx.x * blockDim.x + threadIdx.x;
    if (i < n) rowptr[i] += bsum[i >> 10];
    if (i == 0) rowptr[n] = E;
}

// ---- per-replica sub-cursors within each node's segment ----
__global__ void k_cursor(const int* __restrict__ rowptr, const int* __restrict__ ci4,
                         int* __restrict__ cur4, int n) {
    int i = blockIdx.x * blockDim.x + threadIdx.x;
    if (i < n) {
        int b = rowptr[i];
        int c0 = ci4[i], c1 = ci4[NN + i], c2 = ci4[2 * NN + i];
        cur4[i] = b;
        cur4[NN + i] = b + c0;
        cur4[2 * NN + i] = b + c0 + c1;
        cur4[3 * NN + i] = b + c0 + c1 + c2;
    }
}

// ---- CSR fill: bucket edges by dst, packed (src, weight) 8B store ----
__global__ void k_fill(const int* __restrict__ src, const int* __restrict__ dst,
                       const float* __restrict__ ew, int* __restrict__ cur4,
                       int2* __restrict__ cw, int E) {
    int e = blockIdx.x * blockDim.x + threadIdx.x;
    if (e < E) {
        int d = dst[e];
        int r = (threadIdx.x & 3) * NN;
        int p = atomicAdd(&cur4[r + d], 1);
        cw[p] = make_int2(src[e], __float_as_int(ew[e]));
    }
}

// ---- gather-reduce v2: one wave per dst node, 16 lanes per edge, 4 edges in flight ----
__global__ void k_gather(const int* __restrict__ rowptr, const int2* __restrict__ cw,
                         const float* __restrict__ xs, float* __restrict__ agg,
                         int n, int E) {
    int node = blockIdx.x * (blockDim.x >> 6) + (threadIdx.x >> 6);
    int lane = threadIdx.x & 63;
    if (node >= n) return;
    int g = lane >> 4;        // edge slot 0..3
    int q = lane & 15;        // feature quad: features 4q..4q+3
    int beg = rowptr[node], end = rowptr[node + 1];
    float4 acc = make_float4(0.f, 0.f, 0.f, 0.f);
    #pragma unroll 2
    for (int base = beg; base < end; base += 4) {
        int e = base + g;
        int ee = min(e, E - 1);
        int2 cwv = cw[ee];                       // broadcast within 16-lane group
        float w = (e < end) ? __int_as_float(cwv.y) : 0.f;
        const float4* row = (const float4*)(xs + (size_t)cwv.x * D);
        float4 v = row[q];
        acc.x += w * v.x; acc.y += w * v.y; acc.z += w * v.z; acc.w += w * v.w;
    }
    // reduce over the 4 edge slots (xor 16, 32)
    acc.x += __shfl_xor(acc.x, 16); acc.y += __shfl_xor(acc.y, 16);
    acc.z += __shfl_xor(acc.z, 16); acc.w += __shfl_xor(acc.w, 16);
    acc.x += __shfl_xor(acc.x, 32); acc.y += __shfl_xor(acc.y, 32);
    acc.z += __shfl_xor(acc.z, 32); acc.w += __shfl_xor(acc.w, 32);
    if (g == 0) ((float4*)(agg + (size_t)node * D))[q] = acc;
}

// ---- node-wise GEMM: out[v] = epilogue( (in[v] * (SCALE_IN?nd[v]:1)) @ W + b ) ----
template<int OUTD, bool RELU, bool SCALE_IN, bool SCALE_OUT, bool ADD_RES>
__global__ void k_gemm(const float* __restrict__ in, const float* __restrict__ W,
                       const float* __restrict__ bias, const float* __restrict__ nd,
                       const float* __restrict__ ns, const float* __restrict__ res,
                       float* __restrict__ out, int n) {
    constexpr int NPB = 256 / OUTD;   // nodes per block
    __shared__ float sW[D * OUTD];
    __shared__ float sIn[NPB][D];
    int tid = threadIdx.x;
    for (int i = tid; i < D * OUTD; i += 256) sW[i] = W[i];
    int node0 = blockIdx.x * NPB;
    for (int i = tid; i < NPB * D; i += 256) {
        int ln = i / D, d = i % D;
        int node = node0 + ln;
        float v = 0.f;
        if (node < n) {
            v = in[(size_t)node * D + d];
            if (SCALE_IN) v *= nd[node];
        }
        sIn[ln][d] = v;
    }
    __syncthreads();
    int ln = tid / OUTD;
    int f = tid % OUTD;
    int node = node0 + ln;
    if (node >= n) return;
    float acc = bias[f];
    #pragma unroll
    for (int d = 0; d < D; ++d)
        acc += sIn[ln][d] * sW[d * OUTD + f];
    if (ADD_RES) acc += res[(size_t)node * OUTD + f];
    if (RELU) acc = fmaxf(acc, 0.f);
    if (SCALE_OUT) acc *= ns[node];
    out[(size_t)node * OUTD + f] = acc;
}

extern "C" void kernel_launch(void* const* d_in, const int* in_sizes, int n_in,
                              void* d_out, int out_size, void* d_ws, size_t ws_size,
                              hipStream_t stream) {
    const float* x   = (const float*)d_in[0];
    const int*   src = (const int*)d_in[1];
    const int*   dst = (const int*)d_in[2];
    const float* ew  = (const float*)d_in[3];
    const float* Wl[4] = {(const float*)d_in[4], (const float*)d_in[6],
                          (const float*)d_in[8], (const float*)d_in[10]};
    const float* bl[4] = {(const float*)d_in[5], (const float*)d_in[7],
                          (const float*)d_in[9], (const float*)d_in[11]};
    const float* Wr = (const float*)d_in[12];
    const float* br = (const float*)d_in[13];
    const float* Wo = (const float*)d_in[14];
    const float* bo = (const float*)d_in[15];
    float* out = (float*)d_out;

    const int N = NN;
    const int E = in_sizes[1];

    // workspace layout; count/cursor arrays ALIAS agg (dead before first gather)
    float* ws     = (float*)d_ws;
    float* norm_s = ws;                          // N
    float* norm_d = norm_s + N;                  // N
    float* xs     = norm_d + N;                  // N*D
    float* agg    = xs + (size_t)N * D;          // N*D
    float* res    = agg + (size_t)N * D;         // N*D
    int*   rowptr = (int*)(res + (size_t)N * D); // N+1
    int*   bsum   = rowptr + N + 1;              // 128
    int2*  cw     = (int2*)(bsum + 128);         // E (packed col+wgt)
    // aliases inside agg (13N ints = 5.2 MB < 25.6 MB):
    int* cnt_o4 = (int*)agg;                     // 4N
    int* cnt_i4 = cnt_o4 + 4 * N;                // 4N
    int* tot_in = cnt_i4 + 4 * N;                // N
    int* cur4   = tot_in + N;                    // 4N

    // ---- degrees + norms ----
    hipMemsetAsync(cnt_o4, 0, 8 * (size_t)N * sizeof(int), stream);
    k_count<<<(E + 255) / 256, 256, 0, stream>>>(src, dst, cnt_o4, cnt_i4, E);
    k_norm<<<(N + 255) / 256, 256, 0, stream>>>(cnt_o4, cnt_i4, norm_s, norm_d, tot_in, N);

    // ---- CSR build (by dst) ----
    int nb = (N + 1023) / 1024;  // 98
    k_scan1<<<nb, 256, 0, stream>>>(tot_in, rowptr, bsum, N);
    k_scan2<<<1, 128, 0, stream>>>(bsum, nb);
    k_scan3<<<(N + 255) / 256, 256, 0, stream>>>(rowptr, bsum, N, E);
    k_cursor<<<(N + 255) / 256, 256, 0, stream>>>(rowptr, cnt_i4, cur4, N);
    k_fill<<<(E + 255) / 256, 256, 0, stream>>>(src, dst, ew, cur4, cw, E);

    // ---- xs = x * norm_s; res = x @ Wr + br ----
    k_scale<<<(N * 16 + 255) / 256, 256, 0, stream>>>(x, norm_s, xs, N * 16);
    k_gemm<64, false, false, false, false><<<(N + 3) / 4, 256, 0, stream>>>(
        x, Wr, br, nullptr, nullptr, nullptr, res, N);

    // ---- 4 GCN layers ----
    for (int l = 0; l < 4; ++l) {
        k_gather<<<(N + 3) / 4, 256, 0, stream>>>(rowptr, cw, xs, agg, N, E);
        if (l < 3) {
            // xs = relu((agg*nd)@W + b) * ns   (pre-scaled for next gather)
            k_gemm<64, true, true, true, false><<<(N + 3) / 4, 256, 0, stream>>>(
                agg, Wl[l], bl[l], norm_d, norm_s, nullptr, xs, N);
        } else {
            // xs = relu((agg*nd)@W4 + b4 + res)
            k_gemm<64, true, true, false, true><<<(N + 3) / 4, 256, 0, stream>>>(
                agg, Wl[l], bl[l], norm_d, nullptr, res, xs, N);
        }
    }
    // ---- out = xs @ Wo + bo ----
    k_gemm<32, false, false, false, false><<<(N + 7) / 8, 256, 0, stream>>>(
        xs, Wo, bo, nullptr, nullptr, nullptr, out, N);
}

// Round 4
// 725.244 us; speedup vs baseline: 8.2956x; 1.2334x over previous
//
#include <hip/hip_runtime.h>

#define NN 100000
#define D 64
#define NX 8   // XCDs

__device__ __forceinline__ int get_xcc() {
    int x;
    asm volatile("s_getreg_b32 %0, hwreg(HW_REG_XCC_ID)" : "=s"(x));
    return x & (NX - 1);
}

__device__ __forceinline__ void atom_add_xcd(int* p, int v) {
    // workgroup-scope: executes in the local XCD L2 (no device-scope bypass).
    __hip_atomic_fetch_add(p, v, __ATOMIC_RELAXED, __HIP_MEMORY_SCOPE_WORKGROUP);
}

// ---- degree counts into per-XCD replicas (L2-local atomics) ----
__global__ void k_count(const int* __restrict__ src, const int* __restrict__ dst,
                        int* __restrict__ cnt_o8, int* __restrict__ cnt_i8, int E) {
    int e = blockIdx.x * blockDim.x + threadIdx.x;
    int x = get_xcc() * NN;
    if (e < E) {
        atom_add_xcd(&cnt_o8[x + src[e]], 1);
        atom_add_xcd(&cnt_i8[x + dst[e]], 1);
    }
}

// ---- norms from replica sums; emit per-node total in-degree ----
__global__ void k_norm(const int* __restrict__ co8, const int* __restrict__ ci8,
                       float* __restrict__ ns, float* __restrict__ nd,
                       int* __restrict__ tot_in, int n) {
    int i = blockIdx.x * blockDim.x + threadIdx.x;
    if (i < n) {
        int o = 0, c = 0;
        #pragma unroll
        for (int x = 0; x < NX; ++x) { o += co8[x * NN + i]; c += ci8[x * NN + i]; }
        ns[i] = rsqrtf(fmaxf((float)o, 1.0f));
        nd[i] = rsqrtf(fmaxf((float)c, 1.0f));
        tot_in[i] = c;
    }
}

// ---- xs = x * norm_s (row-wise), float4 ----
__global__ void k_scale(const float* __restrict__ x, const float* __restrict__ ns,
                        float* __restrict__ xs, int n16) {
    int i = blockIdx.x * blockDim.x + threadIdx.x;
    if (i < n16) {
        float s = ns[i >> 4];
        float4 v = ((const float4*)x)[i];
        v.x *= s; v.y *= s; v.z *= s; v.w *= s;
        ((float4*)xs)[i] = v;
    }
}

// ---- exclusive scan, phase 1: each block scans 1024 ints (256 thr x 4) ----
__global__ void k_scan1(const int* __restrict__ in, int* __restrict__ out,
                        int* __restrict__ bsum, int n) {
    __shared__ int lds[256];
    int t = threadIdx.x;
    int base = blockIdx.x * 1024 + t * 4;
    int a0 = 0, a1 = 0, a2 = 0, a3 = 0;
    if (base + 3 < n) {
        int4 v = *(const int4*)(in + base);
        a0 = v.x; a1 = v.y; a2 = v.z; a3 = v.w;
    } else {
        if (base + 0 < n) a0 = in[base + 0];
        if (base + 1 < n) a1 = in[base + 1];
        if (base + 2 < n) a2 = in[base + 2];
        if (base + 3 < n) a3 = in[base + 3];
    }
    lds[t] = a0 + a1 + a2 + a3;
    __syncthreads();
    for (int off = 1; off < 256; off <<= 1) {
        int val = lds[t];
        int add = (t >= off) ? lds[t - off] : 0;
        __syncthreads();
        lds[t] = val + add;
        __syncthreads();
    }
    if (t == 255) bsum[blockIdx.x] = lds[255];
    int o0 = (t > 0) ? lds[t - 1] : 0;
    int o1 = o0 + a0, o2 = o1 + a1, o3 = o2 + a2;
    if (base + 0 < n) out[base + 0] = o0;
    if (base + 1 < n) out[base + 1] = o1;
    if (base + 2 < n) out[base + 2] = o2;
    if (base + 3 < n) out[base + 3] = o3;
}

// ---- phase 2: exclusive scan of block sums (nb <= 128), one block ----
__global__ void k_scan2(int* __restrict__ bsum, int nb) {
    __shared__ int lds[128];
    int t = threadIdx.x;
    lds[t] = (t < nb) ? bsum[t] : 0;
    __syncthreads();
    for (int off = 1; off < 128; off <<= 1) {
        int val = lds[t];
        int add = (t >= off) ? lds[t - off] : 0;
        __syncthreads();
        lds[t] = val + add;
        __syncthreads();
    }
    if (t < nb) bsum[t] = (t > 0) ? lds[t - 1] : 0;
}

// ---- phase 3: add block offsets; rowptr[n] = E ----
__global__ void k_scan3(int* __restrict__ rowptr, const int* __restrict__ bsum,
                        int n, int E) {
    int i = blockIdx.x * blockDim.x + threadIdx.x;
    if (i < n) rowptr[i] += bsum[i >> 10];
    if (i == 0) rowptr[n] = E;
}

// ---- per-XCD sub-cursors within each node's segment ----
__global__ void k_cursor(const int* __restrict__ rowptr, const int* __restrict__ ci8,
                         int* __restrict__ cur8, int n) {
    int i = blockIdx.x * blockDim.x + threadIdx.x;
    if (i < n) {
        int run = rowptr[i];
        #pragma unroll
        for (int x = 0; x < NX; ++x) {
            cur8[x * NN + i] = run;
            run += ci8[x * NN + i];
        }
    }
}

// ---- CSR fill: bucket edges by dst, L2-local cursor atomics ----
__global__ void k_fill(const int* __restrict__ src, const int* __restrict__ dst,
                       const float* __restrict__ ew, int* __restrict__ cur8,
                       int2* __restrict__ cw, int E) {
    int e = blockIdx.x * blockDim.x + threadIdx.x;
    int x = get_xcc() * NN;
    if (e < E) {
        int d = dst[e];
        int p = __hip_atomic_fetch_add(&cur8[x + d], 1, __ATOMIC_RELAXED,
                                       __HIP_MEMORY_SCOPE_WORKGROUP);
        cw[p] = make_int2(src[e], __float_as_int(ew[e]));
    }
}

// ---- gather-reduce: one wave per dst node, 16 lanes per edge, 4 edges in flight ----
__global__ void k_gather(const int* __restrict__ rowptr, const int2* __restrict__ cw,
                         const float* __restrict__ xs, float* __restrict__ agg,
                         int n, int E) {
    int node = blockIdx.x * (blockDim.x >> 6) + (threadIdx.x >> 6);
    int lane = threadIdx.x & 63;
    if (node >= n) return;
    int g = lane >> 4;        // edge slot 0..3
    int q = lane & 15;        // feature quad
    int beg = rowptr[node], end = rowptr[node + 1];
    float4 acc = make_float4(0.f, 0.f, 0.f, 0.f);
    #pragma unroll 2
    for (int base = beg; base < end; base += 4) {
        int e = base + g;
        int ee = min(e, E - 1);
        int2 cwv = cw[ee];
        float w = (e < end) ? __int_as_float(cwv.y) : 0.f;
        const float4* row = (const float4*)(xs + (size_t)cwv.x * D);
        float4 v = row[q];
        acc.x += w * v.x; acc.y += w * v.y; acc.z += w * v.z; acc.w += w * v.w;
    }
    acc.x += __shfl_xor(acc.x, 16); acc.y += __shfl_xor(acc.y, 16);
    acc.z += __shfl_xor(acc.z, 16); acc.w += __shfl_xor(acc.w, 16);
    acc.x += __shfl_xor(acc.x, 32); acc.y += __shfl_xor(acc.y, 32);
    acc.z += __shfl_xor(acc.z, 32); acc.w += __shfl_xor(acc.w, 32);
    if (g == 0) ((float4*)(agg + (size_t)node * D))[q] = acc;
}

// ---- register-tiled node GEMM: 64 nodes/block, thread = 4 nodes x 4 feats ----
// out[v] = epilogue( (in[v] * (SCALE_IN?nd[v]:1)) @ W + b ); +res before relu
template<int OUTD, bool RELU, bool SCALE_IN, bool SCALE_OUT, bool ADD_RES>
__global__ void k_gemm(const float* __restrict__ in, const float* __restrict__ W,
                       const float* __restrict__ bias, const float* __restrict__ nd,
                       const float* __restrict__ ns, const float* __restrict__ res,
                       float* __restrict__ out, int n) {
    constexpr int FQ = OUTD / 4;        // feature quads
    constexpr int NT = 16 * FQ;         // threads per block
    __shared__ float sW[D * OUTD];      // [d][f]
    __shared__ float sInT[D][68];       // transposed inputs, padded (2-way max = free)
    int t = threadIdx.x;
    for (int i = t; i < D * OUTD; i += NT) sW[i] = W[i];
    int node0 = blockIdx.x * 64;
    for (int i = t; i < 64 * 16; i += NT) {
        int nloc = i & 63;
        int q = i >> 6;
        int node = node0 + nloc;
        float4 v = make_float4(0.f, 0.f, 0.f, 0.f);
        if (node < n) {
            v = *(const float4*)(in + (size_t)node * D + 4 * q);
            if (SCALE_IN) { float s = nd[node]; v.x *= s; v.y *= s; v.z *= s; v.w *= s; }
        }
        sInT[4 * q + 0][nloc] = v.x;
        sInT[4 * q + 1][nloc] = v.y;
        sInT[4 * q + 2][nloc] = v.z;
        sInT[4 * q + 3][nloc] = v.w;
    }
    __syncthreads();
    int fq = t % FQ, nq = t / FQ;
    float4 a0 = {0,0,0,0}, a1 = {0,0,0,0}, a2 = {0,0,0,0}, a3 = {0,0,0,0};
    #pragma unroll 8
    for (int d = 0; d < D; ++d) {
        float4 wv = *(const float4*)&sW[d * OUTD + 4 * fq];
        float4 bv = *(const float4*)&sInT[d][4 * nq];
        a0.x += wv.x * bv.x; a0.y += wv.y * bv.x; a0.z += wv.z * bv.x; a0.w += wv.w * bv.x;
        a1.x += wv.x * bv.y; a1.y += wv.y * bv.y; a1.z += wv.z * bv.y; a1.w += wv.w * bv.y;
        a2.x += wv.x * bv.z; a2.y += wv.y * bv.z; a2.z += wv.z * bv.z; a2.w += wv.w * bv.z;
        a3.x += wv.x * bv.w; a3.y += wv.y * bv.w; a3.z += wv.z * bv.w; a3.w += wv.w * bv.w;
    }
    float4 bb = *(const float4*)&bias[4 * fq];
    float4 accs[4] = {a0, a1, a2, a3};
    #pragma unroll
    for (int j = 0; j < 4; ++j) {
        int node = node0 + 4 * nq + j;
        if (node >= n) break;
        float4 v = accs[j];
        v.x += bb.x; v.y += bb.y; v.z += bb.z; v.w += bb.w;
        if (ADD_RES) {
            float4 r = *(const float4*)(res + (size_t)node * OUTD + 4 * fq);
            v.x += r.x; v.y += r.y; v.z += r.z; v.w += r.w;
        }
        if (RELU) {
            v.x = fmaxf(v.x, 0.f); v.y = fmaxf(v.y, 0.f);
            v.z = fmaxf(v.z, 0.f); v.w = fmaxf(v.w, 0.f);
        }
        if (SCALE_OUT) {
            float s = ns[node];
            v.x *= s; v.y *= s; v.z *= s; v.w *= s;
        }
        *(float4*)(out + (size_t)node * OUTD + 4 * fq) = v;
    }
}

extern "C" void kernel_launch(void* const* d_in, const int* in_sizes, int n_in,
                              void* d_out, int out_size, void* d_ws, size_t ws_size,
                              hipStream_t stream) {
    const float* x   = (const float*)d_in[0];
    const int*   src = (const int*)d_in[1];
    const int*   dst = (const int*)d_in[2];
    const float* ew  = (const float*)d_in[3];
    const float* Wl[4] = {(const float*)d_in[4], (const float*)d_in[6],
                          (const float*)d_in[8], (const float*)d_in[10]};
    const float* bl[4] = {(const float*)d_in[5], (const float*)d_in[7],
                          (const float*)d_in[9], (const float*)d_in[11]};
    const float* Wr = (const float*)d_in[12];
    const float* br = (const float*)d_in[13];
    const float* Wo = (const float*)d_in[14];
    const float* bo = (const float*)d_in[15];
    float* out = (float*)d_out;

    const int N = NN;
    const int E = in_sizes[1];

    // workspace layout (~91 MB); count/cursor arrays ALIAS agg (dead before gather)
    float* ws     = (float*)d_ws;
    float* norm_s = ws;                          // N
    float* norm_d = norm_s + N;                  // N
    float* xs     = norm_d + N;                  // N*D
    float* agg    = xs + (size_t)N * D;          // N*D
    float* res    = agg + (size_t)N * D;         // N*D
    int*   rowptr = (int*)(res + (size_t)N * D); // N+1
    int*   bsum   = rowptr + N + 1;              // 128
    int2*  cw     = (int2*)(bsum + 128);         // E (packed col+wgt)
    // aliases inside agg (25N ints = 10 MB < 25.6 MB); NN*4B = 6250 full 64B lines,
    // so replicas never share a cacheline across XCDs.
    int* cnt_o8 = (int*)agg;                     // 8N
    int* cnt_i8 = cnt_o8 + NX * N;               // 8N
    int* tot_in = cnt_i8 + NX * N;               // N
    int* cur8   = tot_in + N;                    // 8N

    // ---- degrees + norms (XCD-local atomics) ----
    hipMemsetAsync(cnt_o8, 0, 2 * (size_t)NX * N * sizeof(int), stream);
    k_count<<<(E + 255) / 256, 256, 0, stream>>>(src, dst, cnt_o8, cnt_i8, E);
    k_norm<<<(N + 255) / 256, 256, 0, stream>>>(cnt_o8, cnt_i8, norm_s, norm_d, tot_in, N);

    // ---- CSR build (by dst) ----
    int nb = (N + 1023) / 1024;  // 98
    k_scan1<<<nb, 256, 0, stream>>>(tot_in, rowptr, bsum, N);
    k_scan2<<<1, 128, 0, stream>>>(bsum, nb);
    k_scan3<<<(N + 255) / 256, 256, 0, stream>>>(rowptr, bsum, N, E);
    k_cursor<<<(N + 255) / 256, 256, 0, stream>>>(rowptr, cnt_i8, cur8, N);
    k_fill<<<(E + 255) / 256, 256, 0, stream>>>(src, dst, ew, cur8, cw, E);

    // ---- xs = x * norm_s; res = x @ Wr + br ----
    k_scale<<<(N * 16 + 255) / 256, 256, 0, stream>>>(x, norm_s, xs, N * 16);
    k_gemm<64, false, false, false, false><<<(N + 63) / 64, 256, 0, stream>>>(
        x, Wr, br, nullptr, nullptr, nullptr, res, N);

    // ---- 4 GCN layers ----
    for (int l = 0; l < 4; ++l) {
        k_gather<<<(N + 3) / 4, 256, 0, stream>>>(rowptr, cw, xs, agg, N, E);
        if (l < 3) {
            // xs = relu((agg*nd)@W + b) * ns   (pre-scaled for next gather)
            k_gemm<64, true, true, true, false><<<(N + 63) / 64, 256, 0, stream>>>(
                agg, Wl[l], bl[l], norm_d, norm_s, nullptr, xs, N);
        } else {
            // xs = relu((agg*nd)@W4 + b4 + res)
            k_gemm<64, true, true, false, true><<<(N + 63) / 64, 256, 0, stream>>>(
                agg, Wl[l], bl[l], norm_d, nullptr, res, xs, N);
        }
    }
    // ---- out = xs @ Wo + bo ----
    k_gemm<32, false, false, false, false><<<(N + 63) / 64, 128, 0, stream>>>(
        xs, Wo, bo, nullptr, nullptr, nullptr, out, N);
}

// Round 5
// 485.446 us; speedup vs baseline: 12.3933x; 1.4940x over previous
//
#include <hip/hip_runtime.h>

#define NN 100000
#define D 64
#define G 8        // node-range groups
#define RS 12500   // nodes per range (G*RS == NN)
#define NC 32      // edge chunks
#define NB (G*NC)  // 256 blocks for hist/fill

// ---- bf16 helpers (storage = ushort; unpack is shift/mask only) ----
__device__ __forceinline__ float bf2f_lo(unsigned w) { return __uint_as_float(w << 16); }
__device__ __forceinline__ float bf2f_hi(unsigned w) { return __uint_as_float(w & 0xffff0000u); }
__device__ __forceinline__ unsigned f2bf(float f) {
    unsigned u = __float_as_uint(f);
    return (u + 0x7fffu + ((u >> 16) & 1u)) >> 16;
}
__device__ __forceinline__ unsigned pack2(float a, float b) {
    return f2bf(a) | (f2bf(b) << 16);
}

// ---- per-(chunk,range) LDS histograms of src and dst; NO global atomics ----
__global__ __launch_bounds__(512) void k_hist(const int* __restrict__ src,
                                              const int* __restrict__ dst,
                                              int* __restrict__ part_s,
                                              int* __restrict__ part_d, int E) {
    __shared__ int hs[RS], hd[RS];
    int b = blockIdx.x, t = threadIdx.x;
    int g = b & (G - 1), c = b >> 3;
    int lo = g * RS;
    for (int i = t; i < RS; i += 512) { hs[i] = 0; hd[i] = 0; }
    __syncthreads();
    int e0 = (int)(((long long)c * E / NC) & ~3LL);
    int e1 = (c + 1 == NC) ? E : (int)(((long long)(c + 1) * E / NC) & ~3LL);
    int m = (e1 - e0) & ~2047;          // vectorized span
    for (int e = e0 + t * 4; e < e0 + m; e += 2048) {
        int4 s4 = *(const int4*)(src + e);
        int4 d4 = *(const int4*)(dst + e);
        int s;
        s = s4.x - lo; if ((unsigned)s < RS) atomicAdd(&hs[s], 1);
        s = s4.y - lo; if ((unsigned)s < RS) atomicAdd(&hs[s], 1);
        s = s4.z - lo; if ((unsigned)s < RS) atomicAdd(&hs[s], 1);
        s = s4.w - lo; if ((unsigned)s < RS) atomicAdd(&hs[s], 1);
        s = d4.x - lo; if ((unsigned)s < RS) atomicAdd(&hd[s], 1);
        s = d4.y - lo; if ((unsigned)s < RS) atomicAdd(&hd[s], 1);
        s = d4.z - lo; if ((unsigned)s < RS) atomicAdd(&hd[s], 1);
        s = d4.w - lo; if ((unsigned)s < RS) atomicAdd(&hd[s], 1);
    }
    for (int e = e0 + m + t; e < e1; e += 512) {
        int s = src[e] - lo, d = dst[e] - lo;
        if ((unsigned)s < RS) atomicAdd(&hs[s], 1);
        if ((unsigned)d < RS) atomicAdd(&hd[d], 1);
    }
    __syncthreads();
    int base = b * RS;
    for (int i = t; i < RS; i += 512) {
        part_s[base + i] = hs[i];
        part_d[base + i] = hd[i];
    }
}

// ---- merge partials -> norms + total in-degree ----
__global__ void k_merge(const int* __restrict__ part_s, const int* __restrict__ part_d,
                        float* __restrict__ ns, float* __restrict__ nd,
                        int* __restrict__ tot_in, int n) {
    int i = blockIdx.x * blockDim.x + threadIdx.x;
    if (i >= n) return;
    int g = i / RS, off = i - g * RS;
    int o = 0, cc = 0;
    for (int c = 0; c < NC; ++c) {
        int b = (c << 3) | g;
        o  += part_s[b * RS + off];
        cc += part_d[b * RS + off];
    }
    ns[i] = rsqrtf(fmaxf((float)o, 1.0f));
    nd[i] = rsqrtf(fmaxf((float)cc, 1.0f));
    tot_in[i] = cc;
}

// ---- exclusive scan, phase 1: each block scans 1024 ints (256 thr x 4) ----
__global__ void k_scan1(const int* __restrict__ in, int* __restrict__ out,
                        int* __restrict__ bsum, int n) {
    __shared__ int lds[256];
    int t = threadIdx.x;
    int base = blockIdx.x * 1024 + t * 4;
    int a0 = 0, a1 = 0, a2 = 0, a3 = 0;
    if (base + 3 < n) {
        int4 v = *(const int4*)(in + base);
        a0 = v.x; a1 = v.y; a2 = v.z; a3 = v.w;
    } else {
        if (base + 0 < n) a0 = in[base + 0];
        if (base + 1 < n) a1 = in[base + 1];
        if (base + 2 < n) a2 = in[base + 2];
        if (base + 3 < n) a3 = in[base + 3];
    }
    lds[t] = a0 + a1 + a2 + a3;
    __syncthreads();
    for (int off = 1; off < 256; off <<= 1) {
        int val = lds[t];
        int add = (t >= off) ? lds[t - off] : 0;
        __syncthreads();
        lds[t] = val + add;
        __syncthreads();
    }
    if (t == 255) bsum[blockIdx.x] = lds[255];
    int o0 = (t > 0) ? lds[t - 1] : 0;
    int o1 = o0 + a0, o2 = o1 + a1, o3 = o2 + a2;
    if (base + 0 < n) out[base + 0] = o0;
    if (base + 1 < n) out[base + 1] = o1;
    if (base + 2 < n) out[base + 2] = o2;
    if (base + 3 < n) out[base + 3] = o3;
}

__global__ void k_scan2(int* __restrict__ bsum, int nb) {
    __shared__ int lds[128];
    int t = threadIdx.x;
    lds[t] = (t < nb) ? bsum[t] : 0;
    __syncthreads();
    for (int off = 1; off < 128; off <<= 1) {
        int val = lds[t];
        int add = (t >= off) ? lds[t - off] : 0;
        __syncthreads();
        lds[t] = val + add;
        __syncthreads();
    }
    if (t < nb) bsum[t] = (t > 0) ? lds[t - 1] : 0;
}

__global__ void k_scan3(int* __restrict__ rowptr, const int* __restrict__ bsum,
                        int n, int E) {
    int i = blockIdx.x * blockDim.x + threadIdx.x;
    if (i < n) rowptr[i] += bsum[i >> 10];
    if (i == 0) rowptr[n] = E;
}

// ---- per-(chunk,range) starting cursors: rowptr + prefix over chunk partials ----
__global__ void k_cursor2(const int* __restrict__ rowptr, const int* __restrict__ part_d,
                          int* __restrict__ cur_part, int n) {
    int i = blockIdx.x * blockDim.x + threadIdx.x;
    if (i >= n) return;
    int g = i / RS, off = i - g * RS;
    int run = rowptr[i];
    for (int c = 0; c < NC; ++c) {
        int b = (c << 3) | g;
        cur_part[b * RS + off] = run;
        run += part_d[b * RS + off];
    }
}

// ---- counting-sort fill: LDS cursors only, slots globally unique ----
__global__ __launch_bounds__(512) void k_fillsort(const int* __restrict__ src,
                                                  const int* __restrict__ dst,
                                                  const float* __restrict__ ew,
                                                  const int* __restrict__ cur_part,
                                                  int2* __restrict__ cw, int E) {
    __shared__ int cur[RS];
    int b = blockIdx.x, t = threadIdx.x;
    int g = b & (G - 1), c = b >> 3;
    int lo = g * RS;
    int base = b * RS;
    for (int i = t; i < RS; i += 512) cur[i] = cur_part[base + i];
    __syncthreads();
    int e0 = (int)(((long long)c * E / NC) & ~3LL);
    int e1 = (c + 1 == NC) ? E : (int)(((long long)(c + 1) * E / NC) & ~3LL);
    int m = (e1 - e0) & ~2047;
    for (int e = e0 + t * 4; e < e0 + m; e += 2048) {
        int4 d4 = *(const int4*)(dst + e);
        int d;
        d = d4.x - lo; if ((unsigned)d < RS) { int p = atomicAdd(&cur[d], 1); cw[p] = make_int2(src[e+0], __float_as_int(ew[e+0])); }
        d = d4.y - lo; if ((unsigned)d < RS) { int p = atomicAdd(&cur[d], 1); cw[p] = make_int2(src[e+1], __float_as_int(ew[e+1])); }
        d = d4.z - lo; if ((unsigned)d < RS) { int p = atomicAdd(&cur[d], 1); cw[p] = make_int2(src[e+2], __float_as_int(ew[e+2])); }
        d = d4.w - lo; if ((unsigned)d < RS) { int p = atomicAdd(&cur[d], 1); cw[p] = make_int2(src[e+3], __float_as_int(ew[e+3])); }
    }
    for (int e = e0 + m + t; e < e1; e += 512) {
        int d = dst[e] - lo;
        if ((unsigned)d < RS) {
            int p = atomicAdd(&cur[d], 1);
            cw[p] = make_int2(src[e], __float_as_int(ew[e]));
        }
    }
}

// ---- xs = bf16(x * norm_s) ----
__global__ void k_scale(const float* __restrict__ x, const float* __restrict__ ns,
                        unsigned short* __restrict__ xsb, int n16) {
    int i = blockIdx.x * blockDim.x + threadIdx.x;
    if (i < n16) {
        float s = ns[i >> 4];
        float4 v = ((const float4*)x)[i];
        ((uint2*)xsb)[i] = make_uint2(pack2(v.x * s, v.y * s), pack2(v.z * s, v.w * s));
    }
}

// ---- gather-reduce: one wave per dst node, 8 lanes/edge (bf16 rows), 8 edges in flight ----
__global__ void k_gather(const int* __restrict__ rowptr, const int2* __restrict__ cw,
                         const unsigned short* __restrict__ xsb, float* __restrict__ agg,
                         int n, int E) {
    int node = blockIdx.x * (blockDim.x >> 6) + (threadIdx.x >> 6);
    int lane = threadIdx.x & 63;
    if (node >= n) return;
    int g = lane >> 3;   // edge slot 0..7
    int h = lane & 7;    // feature octet: feats 8h..8h+7
    int beg = rowptr[node], end = rowptr[node + 1];
    float a0=0,a1=0,a2=0,a3=0,a4=0,a5=0,a6=0,a7=0;
    #pragma unroll 2
    for (int base = beg; base < end; base += 8) {
        int e = base + g;
        int ee = min(e, E - 1);
        int2 cwv = cw[ee];
        float w = (e < end) ? __int_as_float(cwv.y) : 0.f;
        uint4 r = *((const uint4*)(xsb + (size_t)cwv.x * D) + h);
        a0 += w * bf2f_lo(r.x); a1 += w * bf2f_hi(r.x);
        a2 += w * bf2f_lo(r.y); a3 += w * bf2f_hi(r.y);
        a4 += w * bf2f_lo(r.z); a5 += w * bf2f_hi(r.z);
        a6 += w * bf2f_lo(r.w); a7 += w * bf2f_hi(r.w);
    }
    #pragma unroll
    for (int msk = 8; msk <= 32; msk <<= 1) {
        a0 += __shfl_xor(a0, msk); a1 += __shfl_xor(a1, msk);
        a2 += __shfl_xor(a2, msk); a3 += __shfl_xor(a3, msk);
        a4 += __shfl_xor(a4, msk); a5 += __shfl_xor(a5, msk);
        a6 += __shfl_xor(a6, msk); a7 += __shfl_xor(a7, msk);
    }
    if (g == 0) {
        float4* o = (float4*)(agg + (size_t)node * D + 8 * h);
        o[0] = make_float4(a0, a1, a2, a3);
        o[1] = make_float4(a4, a5, a6, a7);
    }
}

// ---- register-tiled node GEMM: 64 nodes/block, thread = 4 nodes x 4 feats ----
template<int OUTD, bool RELU, bool SCALE_IN, bool SCALE_OUT, bool ADD_RES,
         bool IN_BF16, bool OUT_BF16>
__global__ void k_gemm(const void* __restrict__ in_, const float* __restrict__ W,
                       const float* __restrict__ bias, const float* __restrict__ nd,
                       const float* __restrict__ ns, const float* __restrict__ res,
                       void* __restrict__ out_, int n) {
    constexpr int FQ = OUTD / 4;
    constexpr int NT = 16 * FQ;
    __shared__ float sW[D * OUTD];
    __shared__ float sInT[D][68];
    int t = threadIdx.x;
    for (int i = t; i < D * OUTD; i += NT) sW[i] = W[i];
    int node0 = blockIdx.x * 64;
    for (int i = t; i < 64 * 16; i += NT) {
        int nloc = i & 63;
        int q = i >> 6;
        int node = node0 + nloc;
        float4 v = make_float4(0.f, 0.f, 0.f, 0.f);
        if (node < n) {
            if (IN_BF16) {
                const unsigned short* inb = (const unsigned short*)in_;
                uint2 r = *((const uint2*)(inb + (size_t)node * D) + q);
                v = make_float4(bf2f_lo(r.x), bf2f_hi(r.x), bf2f_lo(r.y), bf2f_hi(r.y));
            } else {
                v = *((const float4*)((const float*)in_ + (size_t)node * D) + q);
            }
            if (SCALE_IN) { float s = nd[node]; v.x *= s; v.y *= s; v.z *= s; v.w *= s; }
        }
        sInT[4 * q + 0][nloc] = v.x;
        sInT[4 * q + 1][nloc] = v.y;
        sInT[4 * q + 2][nloc] = v.z;
        sInT[4 * q + 3][nloc] = v.w;
    }
    __syncthreads();
    int fq = t % FQ, nq = t / FQ;
    float4 a0 = {0,0,0,0}, a1 = {0,0,0,0}, a2 = {0,0,0,0}, a3 = {0,0,0,0};
    #pragma unroll 8
    for (int d = 0; d < D; ++d) {
        float4 wv = *(const float4*)&sW[d * OUTD + 4 * fq];
        float4 bv = *(const float4*)&sInT[d][4 * nq];
        a0.x += wv.x * bv.x; a0.y += wv.y * bv.x; a0.z += wv.z * bv.x; a0.w += wv.w * bv.x;
        a1.x += wv.x * bv.y; a1.y += wv.y * bv.y; a1.z += wv.z * bv.y; a1.w += wv.w * bv.y;
        a2.x += wv.x * bv.z; a2.y += wv.y * bv.z; a2.z += wv.z * bv.z; a2.w += wv.w * bv.z;
        a3.x += wv.x * bv.w; a3.y += wv.y * bv.w; a3.z += wv.z * bv.w; a3.w += wv.w * bv.w;
    }
    float4 bb = *(const float4*)&bias[4 * fq];
    float4 accs[4] = {a0, a1, a2, a3};
    #pragma unroll
    for (int j = 0; j < 4; ++j) {
        int node = node0 + 4 * nq + j;
        if (node >= n) break;
        float4 v = accs[j];
        v.x += bb.x; v.y += bb.y; v.z += bb.z; v.w += bb.w;
        if (ADD_RES) {
            float4 r = *(const float4*)(res + (size_t)node * OUTD + 4 * fq);
            v.x += r.x; v.y += r.y; v.z += r.z; v.w += r.w;
        }
        if (RELU) {
            v.x = fmaxf(v.x, 0.f); v.y = fmaxf(v.y, 0.f);
            v.z = fmaxf(v.z, 0.f); v.w = fmaxf(v.w, 0.f);
        }
        if (SCALE_OUT) {
            float s = ns[node];
            v.x *= s; v.y *= s; v.z *= s; v.w *= s;
        }
        if (OUT_BF16) {
            unsigned short* ob = (unsigned short*)out_;
            *((uint2*)(ob + (size_t)node * OUTD) + fq) =
                make_uint2(pack2(v.x, v.y), pack2(v.z, v.w));
        } else {
            *((float4*)((float*)out_ + (size_t)node * OUTD) + fq) = v;
        }
    }
}

extern "C" void kernel_launch(void* const* d_in, const int* in_sizes, int n_in,
                              void* d_out, int out_size, void* d_ws, size_t ws_size,
                              hipStream_t stream) {
    const float* x   = (const float*)d_in[0];
    const int*   src = (const int*)d_in[1];
    const int*   dst = (const int*)d_in[2];
    const float* ew  = (const float*)d_in[3];
    const float* Wl[4] = {(const float*)d_in[4], (const float*)d_in[6],
                          (const float*)d_in[8], (const float*)d_in[10]};
    const float* bl[4] = {(const float*)d_in[5], (const float*)d_in[7],
                          (const float*)d_in[9], (const float*)d_in[11]};
    const float* Wr = (const float*)d_in[12];
    const float* br = (const float*)d_in[13];
    const float* Wo = (const float*)d_in[14];
    const float* bo = (const float*)d_in[15];
    float* out = (float*)d_out;

    const int N = NN;
    const int E = in_sizes[1];

    // ---- workspace layout (words) ~78 MB ----
    float* ws     = (float*)d_ws;
    float* norm_s = ws;                                    // N
    float* norm_d = norm_s + N;                            // N
    int*   rowptr = (int*)(norm_d + N);                    // N+1 (pad to N+64)
    unsigned short* xs = (unsigned short*)(rowptr + N + 64); // N*D bf16 = 32N words
    float* agg    = (float*)(xs + (size_t)N * D);          // 64N words
    float* res    = agg + (size_t)N * D;                   // 64N words
    int2*  cw     = (int2*)(res + (size_t)N * D);          // E int2 = 2E words
    int*   bsum   = (int*)(cw + E);                        // 128
    // aliases: hist partials fill agg exactly (NB*RS*2 = 6.4M = 64N words)
    int* part_s   = (int*)agg;                             // NB*RS
    int* part_d   = part_s + NB * RS;                      // NB*RS
    int* cur_part = part_s;                                // reuse after k_merge
    int* tot_in   = (int*)res;                             // N (dead before res-gemm)

    // ---- degrees via LDS histograms (no global atomics) ----
    k_hist<<<NB, 512, 0, stream>>>(src, dst, part_s, part_d, E);
    k_merge<<<(N + 255) / 256, 256, 0, stream>>>(part_s, part_d, norm_s, norm_d, tot_in, N);

    // ---- rowptr = exclusive_scan(tot_in) ----
    int nb = (N + 1023) / 1024;  // 98
    k_scan1<<<nb, 256, 0, stream>>>(tot_in, rowptr, bsum, N);
    k_scan2<<<1, 128, 0, stream>>>(bsum, nb);
    k_scan3<<<(N + 255) / 256, 256, 0, stream>>>(rowptr, bsum, N, E);

    // ---- counting-sort CSR fill (LDS cursors only) ----
    k_cursor2<<<(N + 255) / 256, 256, 0, stream>>>(rowptr, part_d, cur_part, N);
    k_fillsort<<<NB, 512, 0, stream>>>(src, dst, ew, cur_part, cw, E);

    // ---- xs = bf16(x * norm_s); res = x @ Wr + br ----
    k_scale<<<(N * 16 + 255) / 256, 256, 0, stream>>>(x, norm_s, xs, N * 16);
    k_gemm<64, false, false, false, false, false, false><<<(N + 63) / 64, 256, 0, stream>>>(
        x, Wr, br, nullptr, nullptr, nullptr, res, N);

    // ---- 4 GCN layers ----
    for (int l = 0; l < 4; ++l) {
        k_gather<<<(N + 3) / 4, 256, 0, stream>>>(rowptr, cw, xs, agg, N, E);
        if (l < 3) {
            // xs = bf16( relu((agg*nd)@W + b) * ns )
            k_gemm<64, true, true, true, false, false, true><<<(N + 63) / 64, 256, 0, stream>>>(
                agg, Wl[l], bl[l], norm_d, norm_s, nullptr, xs, N);
        } else {
            // xs = bf16( relu((agg*nd)@W4 + b4 + res) )
            k_gemm<64, true, true, false, true, false, true><<<(N + 63) / 64, 256, 0, stream>>>(
                agg, Wl[l], bl[l], norm_d, nullptr, res, xs, N);
        }
    }
    // ---- out = xs @ Wo + bo ----
    k_gemm<32, false, false, false, false, true, false><<<(N + 63) / 64, 128, 0, stream>>>(
        xs, Wo, bo, nullptr, nullptr, nullptr, out, N);
}

// Round 6
// 471.231 us; speedup vs baseline: 12.7672x; 1.0302x over previous
//
#include <hip/hip_runtime.h>

#define NN 100000
#define D 64
#define G 4        // node-range groups
#define RS 25000   // nodes per range (G*RS == NN)
#define NC 64      // edge chunks
#define NB (G*NC)  // 256 blocks for hist/fill

// ---- bf16 helpers ----
__device__ __forceinline__ float bf2f_lo(unsigned w) { return __uint_as_float(w << 16); }
__device__ __forceinline__ float bf2f_hi(unsigned w) { return __uint_as_float(w & 0xffff0000u); }
__device__ __forceinline__ unsigned f2bf(float f) {
    unsigned u = __float_as_uint(f);
    return (u + 0x7fffu + ((u >> 16) & 1u)) >> 16;
}
__device__ __forceinline__ unsigned pack2(float a, float b) {
    return f2bf(a) | (f2bf(b) << 16);
}

// ---- packed LDS histogram: lo16 = src count, hi16 = dst count ----
__global__ __launch_bounds__(1024) void k_hist(const int* __restrict__ src,
                                               const int* __restrict__ dst,
                                               unsigned* __restrict__ part, int E) {
    __shared__ unsigned h[RS];
    int b = blockIdx.x, t = threadIdx.x;
    int g = b >> 6, c = b & 63;
    int lo = g * RS;
    for (int i = t; i < RS; i += 1024) h[i] = 0;
    __syncthreads();
    int e0 = (int)((((long long)c * E / NC)) & ~3LL);
    int e1 = (c == NC - 1) ? E : (int)((((long long)(c + 1) * E / NC)) & ~3LL);
    int m = (e1 - e0) & ~4095;
    for (int e = e0 + t * 4; e < e0 + m; e += 4096) {
        int4 s4 = *(const int4*)(src + e);
        int4 d4 = *(const int4*)(dst + e);
        int v;
        v = s4.x - lo; if ((unsigned)v < RS) atomicAdd(&h[v], 1u);
        v = s4.y - lo; if ((unsigned)v < RS) atomicAdd(&h[v], 1u);
        v = s4.z - lo; if ((unsigned)v < RS) atomicAdd(&h[v], 1u);
        v = s4.w - lo; if ((unsigned)v < RS) atomicAdd(&h[v], 1u);
        v = d4.x - lo; if ((unsigned)v < RS) atomicAdd(&h[v], 0x10000u);
        v = d4.y - lo; if ((unsigned)v < RS) atomicAdd(&h[v], 0x10000u);
        v = d4.z - lo; if ((unsigned)v < RS) atomicAdd(&h[v], 0x10000u);
        v = d4.w - lo; if ((unsigned)v < RS) atomicAdd(&h[v], 0x10000u);
    }
    for (int e = e0 + m + t; e < e1; e += 1024) {
        int v = src[e] - lo; if ((unsigned)v < RS) atomicAdd(&h[v], 1u);
        v = dst[e] - lo;     if ((unsigned)v < RS) atomicAdd(&h[v], 0x10000u);
    }
    __syncthreads();
    unsigned* pb = part + (size_t)b * RS;
    for (int i = t; i < RS; i += 1024) pb[i] = h[i];
}

// ---- merge partials -> norms; block-scan 1024 in-degrees -> rowptr partial ----
__global__ __launch_bounds__(1024) void k_scan1m(const unsigned* __restrict__ part,
                                                 float* __restrict__ ns, float* __restrict__ nd,
                                                 int* __restrict__ rowptr,
                                                 int* __restrict__ bsum, int n) {
    __shared__ int lds[1024];
    int t = threadIdx.x;
    int i = blockIdx.x * 1024 + t;
    int sv = 0, dv = 0;
    if (i < n) {
        int g = i / RS, off = i - g * RS;
        const unsigned* p = part + (size_t)(g * NC) * RS + off;
        #pragma unroll 8
        for (int c = 0; c < NC; ++c) {
            unsigned v = p[(size_t)c * RS];
            sv += (int)(v & 0xffffu);
            dv += (int)(v >> 16);
        }
        ns[i] = rsqrtf(fmaxf((float)sv, 1.0f));
        nd[i] = rsqrtf(fmaxf((float)dv, 1.0f));
    }
    lds[t] = dv;
    __syncthreads();
    for (int off = 1; off < 1024; off <<= 1) {
        int v = lds[t];
        int a = (t >= off) ? lds[t - off] : 0;
        __syncthreads();
        lds[t] = v + a;
        __syncthreads();
    }
    if (t == 1023) bsum[blockIdx.x] = lds[1023];
    if (i < n) rowptr[i] = lds[t] - dv;   // exclusive
}

// ---- exclusive scan of block sums (nb <= 128), one block ----
__global__ void k_scan2(int* __restrict__ bsum, int nb) {
    __shared__ int lds[128];
    int t = threadIdx.x;
    lds[t] = (t < nb) ? bsum[t] : 0;
    __syncthreads();
    for (int off = 1; off < 128; off <<= 1) {
        int val = lds[t];
        int add = (t >= off) ? lds[t - off] : 0;
        __syncthreads();
        lds[t] = val + add;
        __syncthreads();
    }
    if (t < nb) bsum[t] = (t > 0) ? lds[t - 1] : 0;
}

// ---- finalize rowptr + build per-(range,chunk) cursors ----
__global__ void k_scan3c(int* __restrict__ rowptr, const int* __restrict__ bsum,
                         const unsigned* __restrict__ part, int* __restrict__ cur_part,
                         int n, int E) {
    int i = blockIdx.x * blockDim.x + threadIdx.x;
    if (i == 0) rowptr[n] = E;
    if (i >= n) return;
    int r = rowptr[i] + bsum[i >> 10];
    rowptr[i] = r;
    int g = i / RS, off = i - g * RS;
    const unsigned* p = part + (size_t)(g * NC) * RS + off;
    int* cp = cur_part + (size_t)(g * NC) * RS + off;
    int run = r;
    #pragma unroll 8
    for (int c = 0; c < NC; ++c) {
        cp[(size_t)c * RS] = run;
        run += (int)(p[(size_t)c * RS] >> 16);
    }
}

// ---- counting-sort fill: LDS cursors, vectorized unconditional loads ----
__global__ __launch_bounds__(1024) void k_fillsort(const int* __restrict__ src,
                                                   const int* __restrict__ dst,
                                                   const float* __restrict__ ew,
                                                   const int* __restrict__ cur_part,
                                                   int2* __restrict__ cw, int E) {
    __shared__ int cur[RS];
    int b = blockIdx.x, t = threadIdx.x;
    int g = b >> 6, c = b & 63;
    int lo = g * RS;
    const int* cp = cur_part + (size_t)b * RS;
    for (int i = t; i < RS; i += 1024) cur[i] = cp[i];
    __syncthreads();
    int e0 = (int)((((long long)c * E / NC)) & ~3LL);
    int e1 = (c == NC - 1) ? E : (int)((((long long)(c + 1) * E / NC)) & ~3LL);
    int m = (e1 - e0) & ~4095;
    for (int e = e0 + t * 4; e < e0 + m; e += 4096) {
        int4 s4 = *(const int4*)(src + e);
        int4 d4 = *(const int4*)(dst + e);
        float4 w4 = *(const float4*)(ew + e);
        int d;
        d = d4.x - lo; if ((unsigned)d < RS) { int p = atomicAdd(&cur[d], 1); cw[p] = make_int2(s4.x, __float_as_int(w4.x)); }
        d = d4.y - lo; if ((unsigned)d < RS) { int p = atomicAdd(&cur[d], 1); cw[p] = make_int2(s4.y, __float_as_int(w4.y)); }
        d = d4.z - lo; if ((unsigned)d < RS) { int p = atomicAdd(&cur[d], 1); cw[p] = make_int2(s4.z, __float_as_int(w4.z)); }
        d = d4.w - lo; if ((unsigned)d < RS) { int p = atomicAdd(&cur[d], 1); cw[p] = make_int2(s4.w, __float_as_int(w4.w)); }
    }
    for (int e = e0 + m + t; e < e1; e += 1024) {
        int d = dst[e] - lo;
        if ((unsigned)d < RS) {
            int p = atomicAdd(&cur[d], 1);
            cw[p] = make_int2(src[e], __float_as_int(ew[e]));
        }
    }
}

// ---- xs = bf16(x * norm_s) ----
__global__ void k_scale(const float* __restrict__ x, const float* __restrict__ ns,
                        unsigned short* __restrict__ xsb, int n16) {
    int i = blockIdx.x * blockDim.x + threadIdx.x;
    if (i < n16) {
        float s = ns[i >> 4];
        float4 v = ((const float4*)x)[i];
        ((uint2*)xsb)[i] = make_uint2(pack2(v.x * s, v.y * s), pack2(v.z * s, v.w * s));
    }
}

// ---- gather-reduce + full epilogue: out_v = bf16( post( nd*sum(w*t_src) + b ) ) ----
// !LAST: post = relu(.)*ns ;  LAST: post = relu(. + res)
template<bool LAST>
__global__ void k_gather(const int* __restrict__ rowptr, const int2* __restrict__ cw,
                         const unsigned short* __restrict__ tmat,
                         const float* __restrict__ nd, const float* __restrict__ ns,
                         const float* __restrict__ bias,
                         const unsigned short* __restrict__ resb,
                         unsigned short* __restrict__ outb, int n, int E) {
    int node = blockIdx.x * (blockDim.x >> 6) + (threadIdx.x >> 6);
    int lane = threadIdx.x & 63;
    if (node >= n) return;
    int g = lane >> 3;   // edge slot 0..7
    int h = lane & 7;    // feature octet
    int beg = rowptr[node], end = rowptr[node + 1];
    float a0=0,a1=0,a2=0,a3=0,a4=0,a5=0,a6=0,a7=0;
    #pragma unroll 2
    for (int base = beg; base < end; base += 8) {
        int e = base + g;
        int ee = min(e, E - 1);
        int2 cv = cw[ee];
        float w = (e < end) ? __int_as_float(cv.y) : 0.f;
        uint4 r = *((const uint4*)(tmat + (size_t)cv.x * D) + h);
        a0 += w * bf2f_lo(r.x); a1 += w * bf2f_hi(r.x);
        a2 += w * bf2f_lo(r.y); a3 += w * bf2f_hi(r.y);
        a4 += w * bf2f_lo(r.z); a5 += w * bf2f_hi(r.z);
        a6 += w * bf2f_lo(r.w); a7 += w * bf2f_hi(r.w);
    }
    #pragma unroll
    for (int msk = 8; msk <= 32; msk <<= 1) {
        a0 += __shfl_xor(a0, msk); a1 += __shfl_xor(a1, msk);
        a2 += __shfl_xor(a2, msk); a3 += __shfl_xor(a3, msk);
        a4 += __shfl_xor(a4, msk); a5 += __shfl_xor(a5, msk);
        a6 += __shfl_xor(a6, msk); a7 += __shfl_xor(a7, msk);
    }
    float ndv = nd[node];
    float4 b0 = *(const float4*)(bias + 8 * h);
    float4 b1 = *(const float4*)(bias + 8 * h + 4);
    float v0 = ndv * a0 + b0.x, v1 = ndv * a1 + b0.y;
    float v2 = ndv * a2 + b0.z, v3 = ndv * a3 + b0.w;
    float v4 = ndv * a4 + b1.x, v5 = ndv * a5 + b1.y;
    float v6 = ndv * a6 + b1.z, v7 = ndv * a7 + b1.w;
    if (LAST) {
        uint4 r = *((const uint4*)(resb + (size_t)node * D) + h);
        v0 += bf2f_lo(r.x); v1 += bf2f_hi(r.x);
        v2 += bf2f_lo(r.y); v3 += bf2f_hi(r.y);
        v4 += bf2f_lo(r.z); v5 += bf2f_hi(r.z);
        v6 += bf2f_lo(r.w); v7 += bf2f_hi(r.w);
    }
    v0 = fmaxf(v0, 0.f); v1 = fmaxf(v1, 0.f); v2 = fmaxf(v2, 0.f); v3 = fmaxf(v3, 0.f);
    v4 = fmaxf(v4, 0.f); v5 = fmaxf(v5, 0.f); v6 = fmaxf(v6, 0.f); v7 = fmaxf(v7, 0.f);
    if (!LAST) {
        float s = ns[node];
        v0 *= s; v1 *= s; v2 *= s; v3 *= s; v4 *= s; v5 *= s; v6 *= s; v7 *= s;
    }
    if (g == 0) {
        uint4 o = make_uint4(pack2(v0, v1), pack2(v2, v3), pack2(v4, v5), pack2(v6, v7));
        *((uint4*)(outb + (size_t)node * D) + h) = o;
    }
}

// ---- register-tiled node GEMM: 64 nodes/block, thread = 4 nodes x 4 feats ----
template<int OUTD, bool BIAS, bool IN_BF16, bool OUT_BF16>
__global__ void k_gemm(const void* __restrict__ in_, const float* __restrict__ W,
                       const float* __restrict__ bias, void* __restrict__ out_, int n) {
    constexpr int FQ = OUTD / 4;
    constexpr int NT = 16 * FQ;
    __shared__ float sW[D * OUTD];
    __shared__ float sInT[D][68];
    int t = threadIdx.x;
    for (int i = t; i < D * OUTD; i += NT) sW[i] = W[i];
    int node0 = blockIdx.x * 64;
    for (int i = t; i < 64 * 16; i += NT) {
        int nloc = i & 63;
        int q = i >> 6;
        int node = node0 + nloc;
        float4 v = make_float4(0.f, 0.f, 0.f, 0.f);
        if (node < n) {
            if (IN_BF16) {
                const unsigned short* inb = (const unsigned short*)in_;
                uint2 r = *((const uint2*)(inb + (size_t)node * D) + q);
                v = make_float4(bf2f_lo(r.x), bf2f_hi(r.x), bf2f_lo(r.y), bf2f_hi(r.y));
            } else {
                v = *((const float4*)((const float*)in_ + (size_t)node * D) + q);
            }
        }
        sInT[4 * q + 0][nloc] = v.x;
        sInT[4 * q + 1][nloc] = v.y;
        sInT[4 * q + 2][nloc] = v.z;
        sInT[4 * q + 3][nloc] = v.w;
    }
    __syncthreads();
    int fq = t % FQ, nq = t / FQ;
    float4 a0 = {0,0,0,0}, a1 = {0,0,0,0}, a2 = {0,0,0,0}, a3 = {0,0,0,0};
    #pragma unroll 8
    for (int d = 0; d < D; ++d) {
        float4 wv = *(const float4*)&sW[d * OUTD + 4 * fq];
        float4 bv = *(const float4*)&sInT[d][4 * nq];
        a0.x += wv.x * bv.x; a0.y += wv.y * bv.x; a0.z += wv.z * bv.x; a0.w += wv.w * bv.x;
        a1.x += wv.x * bv.y; a1.y += wv.y * bv.y; a1.z += wv.z * bv.y; a1.w += wv.w * bv.y;
        a2.x += wv.x * bv.z; a2.y += wv.y * bv.z; a2.z += wv.z * bv.z; a2.w += wv.w * bv.z;
        a3.x += wv.x * bv.w; a3.y += wv.y * bv.w; a3.z += wv.z * bv.w; a3.w += wv.w * bv.w;
    }
    float4 bb = make_float4(0.f, 0.f, 0.f, 0.f);
    if (BIAS) bb = *(const float4*)&bias[4 * fq];
    float4 accs[4] = {a0, a1, a2, a3};
    #pragma unroll
    for (int j = 0; j < 4; ++j) {
        int node = node0 + 4 * nq + j;
        if (node >= n) break;
        float4 v = accs[j];
        if (BIAS) { v.x += bb.x; v.y += bb.y; v.z += bb.z; v.w += bb.w; }
        if (OUT_BF16) {
            unsigned short* ob = (unsigned short*)out_;
            *((uint2*)(ob + (size_t)node * OUTD) + fq) =
                make_uint2(pack2(v.x, v.y), pack2(v.z, v.w));
        } else {
            *((float4*)((float*)out_ + (size_t)node * OUTD) + fq) = v;
        }
    }
}

static inline char* align_up(char* p, size_t a) {
    return (char*)(((uintptr_t)p + a - 1) & ~(uintptr_t)(a - 1));
}

extern "C" void kernel_launch(void* const* d_in, const int* in_sizes, int n_in,
                              void* d_out, int out_size, void* d_ws, size_t ws_size,
                              hipStream_t stream) {
    const float* x   = (const float*)d_in[0];
    const int*   src = (const int*)d_in[1];
    const int*   dst = (const int*)d_in[2];
    const float* ew  = (const float*)d_in[3];
    const float* Wl[4] = {(const float*)d_in[4], (const float*)d_in[6],
                          (const float*)d_in[8], (const float*)d_in[10]};
    const float* bl[4] = {(const float*)d_in[5], (const float*)d_in[7],
                          (const float*)d_in[9], (const float*)d_in[11]};
    const float* Wr = (const float*)d_in[12];
    const float* br = (const float*)d_in[13];
    const float* Wo = (const float*)d_in[14];
    const float* bo = (const float*)d_in[15];
    float* out = (float*)d_out;

    const int N = NN;
    const int E = in_sizes[1];

    // ---- workspace (all pointers 256B-aligned); total ~66 MB ----
    char* p = (char*)d_ws;
    float* norm_s = (float*)p;            p = align_up(p + N * 4, 256);
    float* norm_d = (float*)p;            p = align_up(p + N * 4, 256);
    int*   rowptr = (int*)p;              p = align_up(p + (N + 1) * 4, 256);
    int*   bsum   = (int*)p;              p = align_up(p + 128 * 4, 256);
    int2*  cw     = (int2*)p;             p = align_up(p + (size_t)E * 8, 256);
    unsigned* part = (unsigned*)p;        p = align_up(p + (size_t)NB * RS * 4, 256);
    int* cur_part  = (int*)p;             p = align_up(p + (size_t)NB * RS * 4, 256);
    // aliases: part (25.6 MB) holds xs+t (12.8+12.8) once CSR build is done;
    // cur_part (25.6 MB) holds resb (12.8) once fillsort is done.
    unsigned short* xs   = (unsigned short*)part;
    unsigned short* tmat = xs + (size_t)N * D;
    unsigned short* resb = (unsigned short*)cur_part;

    // ---- CSR build: hist -> scan(+norms) -> cursors -> counting-sort fill ----
    k_hist<<<NB, 1024, 0, stream>>>(src, dst, part, E);
    int nb = (N + 1023) / 1024;  // 98
    k_scan1m<<<nb, 1024, 0, stream>>>(part, norm_s, norm_d, rowptr, bsum, N);
    k_scan2<<<1, 128, 0, stream>>>(bsum, nb);
    k_scan3c<<<(N + 255) / 256, 256, 0, stream>>>(rowptr, bsum, part, cur_part, N, E);
    k_fillsort<<<NB, 1024, 0, stream>>>(src, dst, ew, cur_part, cw, E);

    // ---- xs = bf16(Ds*X); res = bf16(X @ Wr + br) ----
    k_scale<<<(N * 16 + 255) / 256, 256, 0, stream>>>(x, norm_s, xs, N * 16);
    k_gemm<64, true, false, true><<<(N + 63) / 64, 256, 0, stream>>>(x, Wr, br, resb, N);

    // ---- 4 GCN layers: t = xs@W (assoc. swap), then gather+epilogue ----
    for (int l = 0; l < 4; ++l) {
        k_gemm<64, false, true, true><<<(N + 63) / 64, 256, 0, stream>>>(
            xs, Wl[l], nullptr, tmat, N);
        if (l < 3) {
            k_gather<false><<<(N + 3) / 4, 256, 0, stream>>>(
                rowptr, cw, tmat, norm_d, norm_s, bl[l], nullptr, xs, N, E);
        } else {
            k_gather<true><<<(N + 3) / 4, 256, 0, stream>>>(
                rowptr, cw, tmat, norm_d, nullptr, bl[l], resb, xs, N, E);
        }
    }
    // ---- out = h4 @ Wo + bo ----
    k_gemm<32, true, true, false><<<(N + 63) / 64, 128, 0, stream>>>(xs, Wo, bo, out, N);
}